// Round 8
// baseline (307.177 us; speedup 1.0000x reference)
//
#include <hip/hip_runtime.h>
#include <hip/hip_bf16.h>
#include <math.h>

#define EPSF 1e-8f
#define LN_EPSF 1e-5f
#define SCALE_QK 0.04419417382415922f   // 512^-0.5

typedef unsigned short ushort_t;
typedef __bf16 bhalf;
typedef bhalf bhalf8 __attribute__((ext_vector_type(8)));
typedef float f32x4 __attribute__((ext_vector_type(4)));

__device__ __forceinline__ float b2f(ushort_t u) {
    return __uint_as_float((unsigned)u << 16);
}
// fp32 -> bf16 RNE (matches numpy/jax rounding)
__device__ __forceinline__ ushort_t f2b(float f) {
    unsigned x = __float_as_uint(f);
    return (ushort_t)((x + 0x7fffu + ((x >> 16) & 1u)) >> 16);
}
// pack two fp32 -> one dword of two bf16 (RNE), lo in bits[15:0]
__device__ __forceinline__ unsigned pk2(float lo, float hi) {
    return (unsigned)f2b(lo) | ((unsigned)f2b(hi) << 16);
}
// async 16B global -> LDS (lands at wave-uniform base + lane*16)
__device__ __forceinline__ void gload16(const ushort_t* g, ushort_t* l) {
    __builtin_amdgcn_global_load_lds(
        (const __attribute__((address_space(1))) unsigned int*)g,
        (__attribute__((address_space(3))) unsigned int*)l, 16, 0, 0);
}

#define WAITV(N) { asm volatile("s_waitcnt vmcnt(" #N ")" ::: "memory"); \
                   __builtin_amdgcn_sched_barrier(0); }
#define FENCE_LGKM { asm volatile("s_waitcnt lgkmcnt(0)" ::: "memory"); \
                     __builtin_amdgcn_sched_barrier(0); }

// ---------------------------------------------------------------------------
// Bias helper vectors: wqbk = Wq@bk, wkbq = Wk@bq, cc = bq.bk.
// grid (32,3), block 256.  (All zero for this problem's inputs, but exact.)
// ---------------------------------------------------------------------------
__global__ __launch_bounds__(256) void mv_bias_kernel(
    const float* __restrict__ Wq, const float* __restrict__ Wk,
    const float* __restrict__ bq, const float* __restrict__ bk,
    float* __restrict__ wqbk, float* __restrict__ wkbq, float* __restrict__ cc)
{
    __shared__ float ls[4];
    const int y = blockIdx.y;
    const int t = threadIdx.x;
    if (y == 2) {
        if (blockIdx.x != 0) return;
        float s = bq[t] * bk[t] + bq[t + 256] * bk[t + 256];
#pragma unroll
        for (int off = 32; off > 0; off >>= 1) s += __shfl_down(s, off, 64);
        int lane = t & 63, w = t >> 6;
        if (lane == 0) ls[w] = s;
        __syncthreads();
        if (t == 0) cc[0] = ls[0] + ls[1] + ls[2] + ls[3];
        return;
    }
    const float* W = y ? Wk : Wq;
    const float* v = y ? bq : bk;
    float* o = y ? wkbq : wqbk;
    const int row = blockIdx.x * 16 + (t >> 4);
    const int l = t & 15;
    const float* wr = W + (size_t)row * 512 + l * 32;
    const float* vr = v + l * 32;
    float s = 0.f;
#pragma unroll
    for (int c = 0; c < 32; ++c) s += wr[c] * vr[c];
#pragma unroll
    for (int off = 8; off > 0; off >>= 1) s += __shfl_down(s, off, 16);
    if (l == 0) o[row] = s;
}

// ---------------------------------------------------------------------------
// LayerNorm: stats + apply + bf16 store + dot with bias helper (t1/t2).
// grid (16384, 2), block 256.  Row = 512 floats, float2 per thread.
// ---------------------------------------------------------------------------
__global__ __launch_bounds__(256) void ln_apply_kernel(
    const float* __restrict__ X1, const float* __restrict__ X2,
    const float* __restrict__ g1, const float* __restrict__ b1,
    const float* __restrict__ g2, const float* __restrict__ b2,
    const float* __restrict__ wb1, const float* __restrict__ wb2,
    ushort_t* __restrict__ O1, ushort_t* __restrict__ O2,
    float* __restrict__ T1, float* __restrict__ T2)
{
    const bool sec = blockIdx.y != 0;
    const float* X = sec ? X2 : X1;
    const float* g = sec ? g2 : g1;
    const float* b = sec ? b2 : b1;
    const float* wb = sec ? wb2 : wb1;
    ushort_t* O = sec ? O2 : O1;
    float* T = sec ? T2 : T1;
    const size_t base = (size_t)blockIdx.x * 512;
    const int t = threadIdx.x;
    float2 x = ((const float2*)(X + base))[t];
    float s = x.x + x.y;
    float q = fmaf(x.x, x.x, x.y * x.y);
#pragma unroll
    for (int off = 32; off > 0; off >>= 1) {
        s += __shfl_down(s, off, 64);
        q += __shfl_down(q, off, 64);
    }
    __shared__ float ls[4], lq[4], mv[2], ld[4];
    int lane = t & 63, w = t >> 6;
    if (lane == 0) { ls[w] = s; lq[w] = q; }
    __syncthreads();
    if (t == 0) {
        float st = ls[0] + ls[1] + ls[2] + ls[3];
        float qt = lq[0] + lq[1] + lq[2] + lq[3];
        float mu = st * (1.0f / 512.0f);
        float var = qt * (1.0f / 512.0f) - mu * mu;
        mv[0] = mu;
        mv[1] = rsqrtf(var + LN_EPSF);
    }
    __syncthreads();
    const float mu = mv[0], rstd = mv[1];
    float2 gg = ((const float2*)g)[t];
    float2 bb = ((const float2*)b)[t];
    float2 ww = ((const float2*)wb)[t];
    float o0 = (x.x - mu) * rstd * gg.x + bb.x;
    float o1 = (x.y - mu) * rstd * gg.y + bb.y;
    ((unsigned*)O)[blockIdx.x * 256 + t] = pk2(o0, o1);
    float d = o0 * ww.x + o1 * ww.y;
#pragma unroll
    for (int off = 32; off > 0; off >>= 1) d += __shfl_down(d, off, 64);
    if (lane == 0) ld[w] = d;
    __syncthreads();
    if (t == 0) T[blockIdx.x] = ld[0] + ld[1] + ld[2] + ld[3];
}

// ---------------------------------------------------------------------------
// Weight prep: z=0,1 cast Wq,Wk -> bf16 (same layout); z=2 transpose Wv.
// grid (16,16,3), block 256.
// ---------------------------------------------------------------------------
__global__ __launch_bounds__(256) void wprep_kernel(
    const float* __restrict__ Wq, const float* __restrict__ Wk,
    const float* __restrict__ Wv,
    ushort_t* __restrict__ Wqb, ushort_t* __restrict__ Wkb,
    ushort_t* __restrict__ WvT)
{
    const int z = blockIdx.z;
    if (z < 2) {
        const float* W = z ? Wk : Wq;
        ushort_t* T = z ? Wkb : Wqb;
        size_t idx = ((size_t)(blockIdx.y * 16 + blockIdx.x)) * 1024 + threadIdx.x * 4;
        float4 f = *(const float4*)(W + idx);
        uint2 u;
        u.x = pk2(f.x, f.y);
        u.y = pk2(f.z, f.w);
        *(uint2*)(T + idx) = u;
        return;
    }
    __shared__ float tile[32][33];
    int tx = threadIdx.x & 31, ty = threadIdx.x >> 5;
    int r0 = blockIdx.y * 32, c0 = blockIdx.x * 32;
#pragma unroll
    for (int p = 0; p < 4; ++p)
        tile[ty + p * 8][tx] = Wv[(size_t)(r0 + ty + p * 8) * 512 + c0 + tx];
    __syncthreads();
#pragma unroll
    for (int p = 0; p < 4; ++p)
        WvT[(size_t)(c0 + ty + p * 8) * 512 + r0 + tx] = f2b(tile[tx][ty + p * 8]);
}

// ---------------------------------------------------------------------------
// colrecip[t] = 1/colsum[t] (+bf16 copy).  16384 elems, grid 64, block 256.
// ---------------------------------------------------------------------------
__global__ __launch_bounds__(256) void colrecip_kernel(
    const float* __restrict__ cs, float* __restrict__ cr,
    ushort_t* __restrict__ crs)
{
    int t = blockIdx.x * 256 + threadIdx.x;
    float r = 1.0f / cs[t];
    cr[t] = r;
    crs[t] = f2b(r);
}

// ---------------------------------------------------------------------------
// 256x256-tile edots GEMM, 512 threads / 8 waves, FINE-GRAINED 4-PHASE
// schedule per K-tile (m201-style): per phase {ds_read register subtile |
// 2 global_load_lds of next tile into other buffer | counted vmcnt |
// s_barrier | lgkmcnt(0) | setprio(1) 16-MFMA quadrant setprio(0) |
// s_barrier}.  Quadrants: q00(af0,b0) q01(af0,b1) q11(af1,b1) q10(af1,b0).
// Stage regions: A_I@ph1, B_I@ph2, B_II@ph3, A_II@ph4 -> every datum issued
// >=2 phases before its guarantee point; uniform WAITV(4) never drains.
//   A_I = LDS stripes {0-7,16-23} (read ph1), A_II = {8-15,24-31} (ph3)
//   B_I = {0-3,8-11,16-19,24-27} (ph1),  B_II = +4 (ph2)
// Guarantee chain: ph4(t) WAITV(4) -> A_I,B_I(t+1) done before ph1(t+1);
// ph1 WAITV(4) -> B_II(t) done before ph2; ph2 WAITV(4) -> A_II(t) before
// ph3.  Barriers make completion workgroup-wide.  nk even, >=4.
// ---------------------------------------------------------------------------
__global__ __launch_bounds__(512) void gemm256_exp_kernel(
    const ushort_t* __restrict__ A, const ushort_t* __restrict__ B,
    ushort_t* __restrict__ Cout,
    const float* __restrict__ t1, const float* __restrict__ t2,
    const float* __restrict__ cc, float* __restrict__ colsum,
    int K, int N, size_t strideA, size_t strideB, size_t strideC,
    float scale)
{
    __shared__ __align__(16) ushort_t As0[256 * 64];   // 32 KB each
    __shared__ __align__(16) ushort_t As1[256 * 64];
    __shared__ __align__(16) ushort_t Bs0[256 * 64];
    __shared__ __align__(16) ushort_t Bs1[256 * 64];
    const int tid = threadIdx.x;

    // XCD-chunked bijective swizzle: grid (8,8,8) -> each XCD owns one batch.
    const int nbx = gridDim.x, nby = gridDim.y;
    const int nwg = nbx * nby * gridDim.z;
    int lin = blockIdx.x + nbx * (blockIdx.y + nby * blockIdx.z);
    int swz = (lin & 7) * (nwg >> 3) + (lin >> 3);
    const int sx = __builtin_ctz(nbx), sy = __builtin_ctz(nby);
    const int bx = swz & (nbx - 1);
    const int by = (swz >> sx) & (nby - 1);
    const int bz = swz >> (sx + sy);

    const ushort_t* Ab = A + strideA * bz;
    const ushort_t* Bb = B + strideB * bz;
    const int m0 = by * 256;
    const int n0 = bx * 256;
    const int wave = tid >> 6;
    const int lane = tid & 63;
    const int fm = lane & 15;
    const int fq = lane >> 4;
    const int fq4 = fq * 4;
    const int wm = (wave >> 2) * 128;      // 2 row-halves
    const int wn = (wave & 3) * 64;        // 4 col-quarters

    const int lrow = lane >> 3;            // 0..7
    const int lchunk = lane & 7;           // 0..7
    const int scs = lchunk ^ lrow;         // swizzled source chunk

    // per-wave stage stripe assignments (2 stripes per wave per region)
    const int aI  = (wave < 4) ? 2 * wave : 2 * wave + 8;    // {0-7,16-23}
    const int aII = (wave < 4) ? 8 + 2 * wave : 16 + 2 * wave; // {8-15,24-31}
    const int bI  = (wave >> 1) * 8 + (wave & 1) * 2;        // {0-3,8-11,..}
    const int bII = bI + 4;

    const int cBase = fq ^ (fm & 7);

    f32x4 acc[8][4];
#pragma unroll
    for (int i = 0; i < 8; ++i)
#pragma unroll
        for (int j = 0; j < 4; ++j) acc[i][j] = (f32x4){0.f, 0.f, 0.f, 0.f};

    auto rdA = [&](const ushort_t* R, int u, int s) {
        return *(const bhalf8*)(R + (wm + u * 16 + fm) * 64 +
                                ((cBase ^ (s << 2)) << 3));
    };
    auto rdB = [&](const ushort_t* R, int u, int s) {
        return *(const bhalf8*)(R + (wn + u * 16 + fm) * 64 +
                                ((cBase ^ (s << 2)) << 3));
    };
    auto stA = [&](ushort_t* W, int s, int k0) {
        gload16(Ab + (size_t)(m0 + s * 8 + lrow) * K + scs * 8 + k0,
                W + s * 512 + lane * 8);
    };
    auto stB = [&](ushort_t* W, int s, int k0) {
        gload16(Bb + (size_t)(n0 + s * 8 + lrow) * K + scs * 8 + k0,
                W + s * 512 + lane * 8);
    };

    bhalf8 af[8], b0[4], b1[4];

#define MFMA_Q(IH, JH, BF)                                                   \
    _Pragma("unroll") for (int s = 0; s < 2; ++s)                            \
    _Pragma("unroll") for (int i = 0; i < 4; ++i)                            \
    _Pragma("unroll") for (int j = 0; j < 2; ++j)                            \
        acc[(IH) * 4 + i][(JH) * 2 + j] =                                    \
            __builtin_amdgcn_mfma_f32_16x16x32_bf16(                         \
                BF[j * 2 + s], af[i * 2 + s], acc[(IH) * 4 + i][(JH) * 2 + j],\
                0, 0, 0);

#define TILE_MAIN(RA, RB, WA, WB, K0N)                                       \
  { /* ph1: read af0,b0 | stage A_I(next) | q00 */                           \
    _Pragma("unroll") for (int u = 0; u < 4; ++u)                            \
    _Pragma("unroll") for (int s = 0; s < 2; ++s) af[u * 2 + s] = rdA(RA, u, s); \
    _Pragma("unroll") for (int u = 0; u < 2; ++u)                            \
    _Pragma("unroll") for (int s = 0; s < 2; ++s) b0[u * 2 + s] = rdB(RB, u, s); \
    stA(WA, aI, K0N); stA(WA, aI + 1, K0N);                                  \
    WAITV(4);                                                                \
    __builtin_amdgcn_s_barrier();                                            \
    FENCE_LGKM;                                                              \
    __builtin_amdgcn_s_setprio(1);                                           \
    MFMA_Q(0, 0, b0);                                                        \
    __builtin_amdgcn_s_setprio(0);                                           \
    __builtin_amdgcn_s_barrier();                                            \
    /* ph2: read b1 | stage B_I(next) | q01 */                               \
    _Pragma("unroll") for (int u = 0; u < 2; ++u)                            \
    _Pragma("unroll") for (int s = 0; s < 2; ++s) b1[u * 2 + s] = rdB(RB, u + 2, s); \
    stB(WB, bI, K0N); stB(WB, bI + 1, K0N);                                  \
    WAITV(4);                                                                \
    __builtin_amdgcn_s_barrier();                                            \
    FENCE_LGKM;                                                              \
    __builtin_amdgcn_s_setprio(1);                                           \
    MFMA_Q(0, 1, b1);                                                        \
    __builtin_amdgcn_s_setprio(0);                                           \
    __builtin_amdgcn_s_barrier();                                            \
    /* ph3: read af1 | stage B_II(next) | q11 */                             \
    _Pragma("unroll") for (int u = 0; u < 4; ++u)                            \
    _Pragma("unroll") for (int s = 0; s < 2; ++s) af[u * 2 + s] = rdA(RA, u + 4, s); \
    stB(WB, bII, K0N); stB(WB, bII + 1, K0N);                                \
    __builtin_amdgcn_s_barrier();                                            \
    FENCE_LGKM;                                                              \
    __builtin_amdgcn_s_setprio(1);                                           \
    MFMA_Q(1, 1, b1);                                                        \
    __builtin_amdgcn_s_setprio(0);                                           \
    __builtin_amdgcn_s_barrier();                                            \
    /* ph4: stage A_II(next) | q10 */                                        \
    stA(WA, aII, K0N); stA(WA, aII + 1, K0N);                                \
    WAITV(4);                                                                \
    __builtin_amdgcn_s_barrier();                                            \
    __builtin_amdgcn_s_setprio(1);                                           \
    MFMA_Q(1, 0, b0);                                                        \
    __builtin_amdgcn_s_setprio(0);                                           \
    __builtin_amdgcn_s_barrier();                                            \
  }

#define TILE_LAST(RA, RB)                                                    \
  { _Pragma("unroll") for (int u = 0; u < 4; ++u)                            \
    _Pragma("unroll") for (int s = 0; s < 2; ++s) af[u * 2 + s] = rdA(RA, u, s); \
    _Pragma("unroll") for (int u = 0; u < 2; ++u)                            \
    _Pragma("unroll") for (int s = 0; s < 2; ++s) b0[u * 2 + s] = rdB(RB, u, s); \
    WAITV(2);                                                                \
    __builtin_amdgcn_s_barrier();                                            \
    FENCE_LGKM;                                                              \
    __builtin_amdgcn_s_setprio(1);                                           \
    MFMA_Q(0, 0, b0);                                                        \
    __builtin_amdgcn_s_setprio(0);                                           \
    __builtin_amdgcn_s_barrier();                                            \
    _Pragma("unroll") for (int u = 0; u < 2; ++u)                            \
    _Pragma("unroll") for (int s = 0; s < 2; ++s) b1[u * 2 + s] = rdB(RB, u + 2, s); \
    WAITV(0);                                                                \
    __builtin_amdgcn_s_barrier();                                            \
    FENCE_LGKM;                                                              \
    __builtin_amdgcn_s_setprio(1);                                           \
    MFMA_Q(0, 1, b1);                                                        \
    __builtin_amdgcn_s_setprio(0);                                           \
    __builtin_amdgcn_s_barrier();                                            \
    _Pragma("unroll") for (int u = 0; u < 4; ++u)                            \
    _Pragma("unroll") for (int s = 0; s < 2; ++s) af[u * 2 + s] = rdA(RA, u + 4, s); \
    __builtin_amdgcn_s_barrier();                                            \
    FENCE_LGKM;                                                              \
    __builtin_amdgcn_s_setprio(1);                                           \
    MFMA_Q(1, 1, b1);                                                        \
    __builtin_amdgcn_s_setprio(0);                                           \
    __builtin_amdgcn_s_barrier();                                            \
    __builtin_amdgcn_s_setprio(1);                                           \
    MFMA_Q(1, 0, b0);                                                        \
    __builtin_amdgcn_s_setprio(0);                                           \
    __builtin_amdgcn_s_barrier();                                            \
  }

    const int nk = K >> 6;                  // 8 for K=512; even, >=4
    // prologue: tile0 -> buf0, issue order A_I,B_I,B_II,A_II (matches steady)
    stA(As0, aI, 0); stA(As0, aI + 1, 0);
    stB(Bs0, bI, 0); stB(Bs0, bI + 1, 0);
    stB(Bs0, bII, 0); stB(Bs0, bII + 1, 0);
    stA(As0, aII, 0); stA(As0, aII + 1, 0);
    WAITV(4);                               // A_I,B_I(0) done
    __builtin_amdgcn_s_barrier();

    for (int t = 0; t < nk - 2; t += 2) {   // tiles 0..nk-3
        TILE_MAIN(As0, Bs0, As1, Bs1, (t + 1) << 6);
        TILE_MAIN(As1, Bs1, As0, Bs0, (t + 2) << 6);
    }
    TILE_MAIN(As0, Bs0, As1, Bs1, (nk - 1) << 6);   // tile nk-2 stages nk-1
    TILE_LAST(As1, Bs1);                             // tile nk-1

#undef TILE_MAIN
#undef TILE_LAST
#undef MFMA_Q

    // Epilogue: exp + bf16 store + colsum (identical math to verified r7).
    ushort_t* C = Cout + strideC * bz;
    const float cv = cc[0];
    f32x4 t2c[4];
#pragma unroll
    for (int nj = 0; nj < 4; ++nj) {
        float4 tv = *(const float4*)(t2 + (size_t)bz * 2048 +
                                     n0 + wn + nj * 16 + fq4);
        t2c[nj][0] = tv.x + cv;
        t2c[nj][1] = tv.y + cv;
        t2c[nj][2] = tv.z + cv;
        t2c[nj][3] = tv.w + cv;
    }
    float psum[4][4];
#pragma unroll
    for (int nj = 0; nj < 4; ++nj)
#pragma unroll
        for (int r = 0; r < 4; ++r) psum[nj][r] = 0.f;
#pragma unroll
    for (int mi = 0; mi < 8; ++mi) {
        const int row = m0 + wm + mi * 16 + fm;
        const float t1v = t1[(size_t)bz * 2048 + row];
        ushort_t* Cr = C + (size_t)row * N + n0 + wn + fq4;
#pragma unroll
        for (int nj = 0; nj < 4; ++nj) {
            ushort_t h0 = f2b(__expf((acc[mi][nj][0] + t1v + t2c[nj][0]) * scale));
            ushort_t h1 = f2b(__expf((acc[mi][nj][1] + t1v + t2c[nj][1]) * scale));
            ushort_t h2 = f2b(__expf((acc[mi][nj][2] + t1v + t2c[nj][2]) * scale));
            ushort_t h3 = f2b(__expf((acc[mi][nj][3] + t1v + t2c[nj][3]) * scale));
            uint2 u;
            u.x = (unsigned)h0 | ((unsigned)h1 << 16);
            u.y = (unsigned)h2 | ((unsigned)h3 << 16);
            *(uint2*)(Cr + nj * 16) = u;
            psum[nj][0] += b2f(h0);
            psum[nj][1] += b2f(h1);
            psum[nj][2] += b2f(h2);
            psum[nj][3] += b2f(h3);
        }
    }
    // reduce over rows within wave (fm = lane bits 0..3)
#pragma unroll
    for (int nj = 0; nj < 4; ++nj)
#pragma unroll
        for (int r = 0; r < 4; ++r) {
            float v = psum[nj][r];
            v += __shfl_xor(v, 1, 64);
            v += __shfl_xor(v, 2, 64);
            v += __shfl_xor(v, 4, 64);
            v += __shfl_xor(v, 8, 64);
            psum[nj][r] = v;
        }
    float* colpart = (float*)&As0[0];
    __syncthreads();
    if (tid < 256) colpart[tid] = 0.f;
    __syncthreads();
    if (fm == 0) {
#pragma unroll
        for (int nj = 0; nj < 4; ++nj)
#pragma unroll
            for (int r = 0; r < 4; ++r)
                atomicAdd(&colpart[wn + nj * 16 + fq4 + r], psum[nj][r]);
    }
    __syncthreads();
    if (tid < 256)
        atomicAdd(&colsum[(size_t)bz * 2048 + n0 + tid], colpart[tid]);
}

// ---------------------------------------------------------------------------
// 256x128-tile OUT GEMM, 512 threads / 8 waves, counted-vmcnt 2-deep
// pipeline (verified r7).  out[m,n] = (sum_k E[m,k] vTs[n,k]) / (rowsum+eps).
// ---------------------------------------------------------------------------
__global__ __launch_bounds__(512) void gemm_out256_kernel(
    const ushort_t* __restrict__ A, const ushort_t* __restrict__ B,
    float* __restrict__ Cout, const ushort_t* __restrict__ crs,
    int K, int N, size_t strideA, size_t strideB, size_t strideC)
{
    __shared__ __align__(16) ushort_t As0[256 * 64];   // 32 KB
    __shared__ __align__(16) ushort_t As1[256 * 64];   // 32 KB
    __shared__ __align__(16) ushort_t Bs0[128 * 64];   // 16 KB
    __shared__ __align__(16) ushort_t Bs1[128 * 64];   // 16 KB
    __shared__ __align__(16) ushort_t crs_lds[2048];   // 4 KB
    const int tid = threadIdx.x;

    // XCD-chunked bijective swizzle: grid (4,8,8) -> each XCD owns one batch.
    const int nbx = gridDim.x, nby = gridDim.y;
    const int nwg = nbx * nby * gridDim.z;
    int lin = blockIdx.x + nbx * (blockIdx.y + nby * blockIdx.z);
    int swz = (lin & 7) * (nwg >> 3) + (lin >> 3);
    const int sx = __builtin_ctz(nbx), sy = __builtin_ctz(nby);
    const int bx = swz & (nbx - 1);
    const int by = (swz >> sx) & (nby - 1);
    const int bz = swz >> (sx + sy);

    const ushort_t* Ab = A + strideA * bz;
    const ushort_t* Bb = B + strideB * bz;
    const int m0 = by * 256;
    const int n0 = bx * 128;
    const int wave = tid >> 6;
    const int lane = tid & 63;
    const int fm = lane & 15;
    const int fq = lane >> 4;
    const int fq4 = fq * 4;
    const int wm = (wave >> 1) * 64;       // 4 row-groups of 64
    const int wn = (wave & 1) * 64;        // 2 col-groups of 64

    const int lrow = lane >> 3;            // 0..7
    const int lchunk = lane & 7;           // 0..7
    const int scs = lchunk ^ lrow;         // swizzled source chunk

    const ushort_t* aSrc[4]; const ushort_t* bSrc[2];
#pragma unroll
    for (int p = 0; p < 4; ++p) {
        int row = wave * 32 + p * 8 + lrow;     // 0..255
        aSrc[p] = Ab + (size_t)(m0 + row) * K + scs * 8;
    }
#pragma unroll
    for (int p = 0; p < 2; ++p) {
        int row = wave * 16 + p * 8 + lrow;     // 0..127
        bSrc[p] = Bb + (size_t)(n0 + row) * K + scs * 8;
    }
    const int aOff = wave * 2048 + lane * 8;    // (wave*32+p*8)*64 + lane*8
    const int bOff = wave * 1024 + lane * 8;    // (wave*16+p*8)*64 + lane*8

    // bf16 colrecip -> LDS (one batch's 2048 entries), then full drain+barrier
    if (tid < 256) {
        uint4 c4 = *(const uint4*)(crs + (size_t)bz * 2048 + tid * 8);
        *(uint4*)&crs_lds[tid * 8] = c4;
    }
    __syncthreads();

    const int cBase = fq ^ (fm & 7);

    f32x4 acc[4][4];
    f32x4 sacc[4];
#pragma unroll
    for (int i = 0; i < 4; ++i) {
        sacc[i] = (f32x4){0.f, 0.f, 0.f, 0.f};
#pragma unroll
        for (int j = 0; j < 4; ++j) acc[i][j] = (f32x4){0.f, 0.f, 0.f, 0.f};
    }

    auto stage = [&](ushort_t* Ad, ushort_t* Bd, int k0) {
#pragma unroll
        for (int p = 0; p < 4; ++p)
            gload16(aSrc[p] + k0, Ad + aOff + p * 512);
#pragma unroll
        for (int p = 0; p < 2; ++p)
            gload16(bSrc[p] + k0, Bd + bOff + p * 512);
    };
    auto compute = [&](const ushort_t* Asb, const ushort_t* Bsb, int k0) {
#pragma unroll
        for (int s = 0; s < 2; ++s) {
            const int off = ((cBase ^ (s << 2)) << 3);
            bhalf8 af[4], bfr[4];
#pragma unroll
            for (int u = 0; u < 4; ++u) {
                af[u]  = *(const bhalf8*)(Asb + (wm + u * 16 + fm) * 64 + off);
                bfr[u] = *(const bhalf8*)(Bsb + (wn + u * 16 + fm) * 64 + off);
            }
#pragma unroll
            for (int i = 0; i < 4; ++i)
#pragma unroll
                for (int j = 0; j < 4; ++j)
                    acc[i][j] = __builtin_amdgcn_mfma_f32_16x16x32_bf16(
                        bfr[j], af[i], acc[i][j], 0, 0, 0);
            bhalf8 bc = *(const bhalf8*)&crs_lds[k0 + (s << 5) + (fq << 3)];
#pragma unroll
            for (int i = 0; i < 4; ++i)
                sacc[i] = __builtin_amdgcn_mfma_f32_16x16x32_bf16(
                    bc, af[i], sacc[i], 0, 0, 0);
        }
    };

    const int nk = K >> 6;                  // 32 (K=2048); even, >=4
    stage(As0, Bs0, 0);
    stage(As1, Bs1, 64);
    for (int t = 0; t < nk - 2; t += 2) {
        WAITV(6);
        __builtin_amdgcn_s_barrier();       // tile t ready
        compute(As0, Bs0, t << 6);
        FENCE_LGKM;
        __builtin_amdgcn_s_barrier();       // all waves done with buf0
        stage(As0, Bs0, (t + 2) << 6);
        WAITV(6);
        __builtin_amdgcn_s_barrier();       // tile t+1 ready
        compute(As1, Bs1, (t + 1) << 6);
        FENCE_LGKM;
        __builtin_amdgcn_s_barrier();       // all waves done with buf1
        stage(As1, Bs1, (t + 3) << 6);
    }
    WAITV(6);
    __builtin_amdgcn_s_barrier();
    compute(As0, Bs0, (nk - 2) << 6);
    WAITV(0);
    __builtin_amdgcn_s_barrier();
    compute(As1, Bs1, (nk - 1) << 6);

    // Epilogue (identical math to verified MODE2): divide by rowsum, f32x4.
    float* C = Cout + strideC * bz;
#pragma unroll
    for (int ti = 0; ti < 4; ++ti) {
        const int row = m0 + wm + ti * 16 + fm;
        const float rs = 1.0f / (sacc[ti][0] + 2.049e-5f);
        float* Cr = C + (size_t)row * N + n0 + wn + fq4;
#pragma unroll
        for (int tj = 0; tj < 4; ++tj) {
            f32x4 v;
#pragma unroll
            for (int r = 0; r < 4; ++r) v[r] = acc[ti][tj][r] * rs;
            *(f32x4*)(Cr + tj * 16) = v;
        }
    }
}

// ---------------------------------------------------------------------------
// NT bf16 MFMA GEMM: C[m,n] = sum_k A[m,k]*B[n,k], k-major bf16, m97-style
// staging (BK=64, global_load_lds 16B, XOR chunk swizzle, conflict-free).
// 128x128 tile, 4 waves, 4x4 MFMA 16x16x32 each, swapped operands.
// XCD-chunked block swizzle (verified r5: FETCH halved).
// MODE 0: plain bf16 store (pk2, 8B)               (M = Wq Wk^T;  KM = cln M^T)
// MODE 3: (acc + bias[row]) * crcol[col], pk2 bf16 store             (vTs)
// ---------------------------------------------------------------------------
template <int MODE>
__global__ __launch_bounds__(256) void mfma_gemm_kernel(
    const ushort_t* __restrict__ A, const ushort_t* __restrict__ B,
    void* __restrict__ Cout,
    const float* __restrict__ bias,     // MODE3: row bias (bv)
    const float* __restrict__ crcol,    // MODE3: f32 colrecip
    int K, int N, size_t strideA, size_t strideB, size_t strideC)
{
    __shared__ __align__(16) ushort_t As[128 * 64];   // 16 KB
    __shared__ __align__(16) ushort_t Bs[128 * 64];   // 16 KB
    const int tid = threadIdx.x;

    // ---- XCD-chunked bijective block swizzle (all dims are powers of 2) ----
    const int nbx = gridDim.x, nby = gridDim.y, nbz = gridDim.z;
    const int nwg = nbx * nby * nbz;
    int bx, by, bz;
    if ((nwg & 7) == 0) {
        int lin = blockIdx.x + nbx * (blockIdx.y + nby * blockIdx.z);
        int swz = (lin & 7) * (nwg >> 3) + (lin >> 3);
        const int sx = __builtin_ctz(nbx), sy = __builtin_ctz(nby);
        bx = swz & (nbx - 1);
        by = (swz >> sx) & (nby - 1);
        bz = swz >> (sx + sy);
    } else {
        bx = blockIdx.x; by = blockIdx.y; bz = blockIdx.z;
    }

    const ushort_t* Ab = A + strideA * bz;
    const ushort_t* Bb = B + strideB * bz;
    const int m0 = by * 128;
    const int n0 = bx * 128;
    const int wave = tid >> 6;
    const int lane = tid & 63;
    const int fm = lane & 15;
    const int fq = lane >> 4;
    const int fq4 = fq * 4;
    const int fm7 = fm & 7;
    const int wm = (wave >> 1) * 64;
    const int wn = (wave & 1) * 64;

    const int lrow = lane >> 3;            // 0..7
    const int lchunk = lane & 7;           // 0..7
    const int scs = lchunk ^ lrow;         // swizzled source chunk

    const ushort_t* aSrc[4]; const ushort_t* bSrc[4];
    ushort_t* aDst[4]; ushort_t* bDst[4];
#pragma unroll
    for (int p = 0; p < 4; ++p) {
        int row = wave * 32 + p * 8 + lrow;
        aSrc[p] = Ab + (size_t)(m0 + row) * K + scs * 8;
        bSrc[p] = Bb + (size_t)(n0 + row) * K + scs * 8;
        aDst[p] = As + (wave * 32 + p * 8) * 64 + lane * 8;
        bDst[p] = Bs + (wave * 32 + p * 8) * 64 + lane * 8;
    }

    const int cBase = fq ^ fm7;
    const ushort_t* aFrag[4]; const ushort_t* bFrag[4];
#pragma unroll
    for (int t = 0; t < 4; ++t) {
        aFrag[t] = As + (wm + t * 16 + fm) * 64;
        bFrag[t] = Bs + (wn + t * 16 + fm) * 64;
    }

    f32x4 acc[4][4];
#pragma unroll
    for (int i = 0; i < 4; ++i)
#pragma unroll
        for (int j = 0; j < 4; ++j) acc[i][j] = (f32x4){0.f, 0.f, 0.f, 0.f};

    for (int k0 = 0; k0 < K; k0 += 64) {
        __syncthreads();
#pragma unroll
        for (int p = 0; p < 4; ++p) {
            gload16(aSrc[p] + k0, aDst[p]);
            gload16(bSrc[p] + k0, bDst[p]);
        }
        __syncthreads();
#pragma unroll
        for (int s = 0; s < 2; ++s) {
            const int off = ((cBase ^ (s << 2)) << 3);
            bhalf8 af[4], bfr[4];
#pragma unroll
            for (int u = 0; u < 4; ++u) {
                af[u]  = *(const bhalf8*)(aFrag[u] + off);
                bfr[u] = *(const bhalf8*)(bFrag[u] + off);
            }
#pragma unroll
            for (int i = 0; i < 4; ++i)
#pragma unroll
                for (int j = 0; j < 4; ++j)
                    acc[i][j] = __builtin_amdgcn_mfma_f32_16x16x32_bf16(
                        bfr[j], af[i], acc[i][j], 0, 0, 0);
        }
    }

    // acc[ti][tj][r] = C[i][j], i = m0+wm+ti*16+fm, j = n0+wn+tj*16+fq4+r
    if (MODE == 3) {
        ushort_t* C = (ushort_t*)Cout + strideC * bz;
        f32x4 crv[4];
#pragma unroll
        for (int tj = 0; tj < 4; ++tj) {
            float4 cq = *(const float4*)(crcol + (size_t)bz * 2048 +
                                         n0 + wn + tj * 16 + fq4);
            crv[tj][0] = cq.x; crv[tj][1] = cq.y;
            crv[tj][2] = cq.z; crv[tj][3] = cq.w;
        }
#pragma unroll
        for (int ti = 0; ti < 4; ++ti) {
            const int row = m0 + wm + ti * 16 + fm;
            const float bvv = bias[row];
            ushort_t* Cr = C + (size_t)row * N + n0 + wn + fq4;
#pragma unroll
            for (int tj = 0; tj < 4; ++tj) {
                uint2 u;
                u.x = pk2((acc[ti][tj][0] + bvv) * crv[tj][0],
                          (acc[ti][tj][1] + bvv) * crv[tj][1]);
                u.y = pk2((acc[ti][tj][2] + bvv) * crv[tj][2],
                          (acc[ti][tj][3] + bvv) * crv[tj][3]);
                *(uint2*)(Cr + tj * 16) = u;
            }
        }
    } else {
        ushort_t* C = (ushort_t*)Cout + strideC * bz;
#pragma unroll
        for (int ti = 0; ti < 4; ++ti) {
            const int row = m0 + wm + ti * 16 + fm;
            ushort_t* Cr = C + (size_t)row * N + n0 + wn + fq4;
#pragma unroll
            for (int tj = 0; tj < 4; ++tj) {
                uint2 u;
                u.x = pk2(acc[ti][tj][0], acc[ti][tj][1]);
                u.y = pk2(acc[ti][tj][2], acc[ti][tj][3]);
                *(uint2*)(Cr + tj * 16) = u;
            }
        }
    }
}

// ---------------------------------------------------------------------------
extern "C" void kernel_launch(void* const* d_in, const int* in_sizes, int n_in,
                              void* d_out, int out_size, void* d_ws, size_t ws_size,
                              hipStream_t stream)
{
    const float* inputs  = (const float*)d_in[0];
    const float* context = (const float*)d_in[1];
    const float* g_in    = (const float*)d_in[2];
    const float* b_in    = (const float*)d_in[3];
    const float* g_ctx   = (const float*)d_in[4];
    const float* b_ctx   = (const float*)d_in[5];
    const float* Wq      = (const float*)d_in[6];
    const float* bq      = (const float*)d_in[7];
    const float* Wk      = (const float*)d_in[8];
    const float* bk      = (const float*)d_in[9];
    const float* Wv      = (const float*)d_in[10];
    const float* bv      = (const float*)d_in[11];
    float* out = (float*)d_out;                      // [8,2048,512] fp32

    const size_t QKV  = 8ull * 2048 * 512;           // 8,388,608
    const size_t WSZ  = 512ull * 512;                // 262,144
    const size_t DOTS = 8ull * 2048 * 2048;          // 33,554,432

    ushort_t* xln   = (ushort_t*)d_ws;
    ushort_t* cln   = xln + QKV;
    ushort_t* Wqb   = cln + QKV;
    ushort_t* Wkb   = Wqb + WSZ;
    ushort_t* WvT   = Wkb + WSZ;
    ushort_t* Mb    = WvT + WSZ;                     // Wq Wk^T, bf16 [512][512]
    ushort_t* KM    = Mb + WSZ;                      // cln M^T [16384][512]
    ushort_t* vTs   = KM + QKV;                      // (cln Wv + bv)^T * cr
    ushort_t* edots = vTs + QKV;
    ushort_t* crs   = edots + DOTS;                  // bf16 colrecip [16384]
    float* fbase    = (float*)(crs + 16384);
    float* colsum   = fbase;                         // 16384
    float* colrecip = colsum + 16384;                // 16384
    float* t1       = colrecip + 16384;              // 16384
    float* t2       = t1 + 16384;                    // 16384
    float* wqbk     = t2 + 16384;                    // 512
    float* wkbq     = wqbk + 512;                    // 512
    float* cc       = wkbq + 512;                    // 1
    size_t need_bytes = (4 * QKV + 4 * WSZ + DOTS + 16384) * 2
                      + (4 * 16384 + 1024 + 1) * 4;
    if (ws_size < need_bytes) return;  // fail loudly via validation mismatch

    hipMemsetAsync(colsum, 0, 16384 * sizeof(float), stream);

    mv_bias_kernel<<<dim3(32, 3), 256, 0, stream>>>(Wq, Wk, bq, bk, wqbk, wkbq, cc);

    ln_apply_kernel<<<dim3(16384, 2), 256, 0, stream>>>(
        inputs, context, g_in, b_in, g_ctx, b_ctx, wqbk, wkbq, xln, cln, t1, t2);

    wprep_kernel<<<dim3(16, 16, 3), 256, 0, stream>>>(Wq, Wk, Wv, Wqb, Wkb, WvT);

    // M = Wq @ Wk^T   [512,512]
    mfma_gemm_kernel<0><<<dim3(4, 4, 1), 256, 0, stream>>>(
        Wqb, Wkb, Mb, nullptr, nullptr,
        512, 512, 0, 0, 0);

    // KM[j][a] = sum_b cln[j,b] M[a,b]   [16384,512]
    mfma_gemm_kernel<0><<<dim3(4, 128, 1), 256, 0, stream>>>(
        cln, Mb, KM, nullptr, nullptr,
        512, 512, 0, 0, 0);

    // edots = exp(scale*(xln KM^T + t1 + t2 + cc)), column sums -> colsum
    gemm256_exp_kernel<<<dim3(8, 8, 8), 512, 0, stream>>>(
        xln, KM, edots, t1, t2, cc, colsum,
        512, 2048, (size_t)2048 * 512, (size_t)2048 * 512, (size_t)2048 * 2048,
        SCALE_QK);

    colrecip_kernel<<<64, 256, 0, stream>>>(colsum, colrecip, crs);

    // vTs[b,d,j] = (sum_b' WvT[d,b'] cln[j,b'] + bv[d]) * colrecip[b,j]
    mfma_gemm_kernel<3><<<dim3(16, 4, 8), 256, 0, stream>>>(
        WvT, cln, vTs, bv, colrecip,
        512, 2048, 0, (size_t)2048 * 512, (size_t)512 * 2048);

    // out = diag(1/(E cr + eps)) * E @ vTs^T   (rowsum via MFMA side-column)
    gemm_out256_kernel<<<dim3(4, 8, 8), 512, 0, stream>>>(
        edots, vTs, out, crs,
        2048, 512, (size_t)2048 * 2048, (size_t)512 * 2048, (size_t)2048 * 512);
}

// Round 9
// 296.919 us; speedup vs baseline: 1.0345x; 1.0345x over previous
//
#include <hip/hip_runtime.h>
#include <hip/hip_bf16.h>
#include <math.h>

#define EPSF 1e-8f
#define LN_EPSF 1e-5f
#define SCALE_QK 0.04419417382415922f   // 512^-0.5

typedef unsigned short ushort_t;
typedef __bf16 bhalf;
typedef bhalf bhalf8 __attribute__((ext_vector_type(8)));
typedef float f32x4 __attribute__((ext_vector_type(4)));

__device__ __forceinline__ float b2f(ushort_t u) {
    return __uint_as_float((unsigned)u << 16);
}
// fp32 -> bf16 RNE (matches numpy/jax rounding)
__device__ __forceinline__ ushort_t f2b(float f) {
    unsigned x = __float_as_uint(f);
    return (ushort_t)((x + 0x7fffu + ((x >> 16) & 1u)) >> 16);
}
// pack two fp32 -> one dword of two bf16 (RNE), lo in bits[15:0]
__device__ __forceinline__ unsigned pk2(float lo, float hi) {
    return (unsigned)f2b(lo) | ((unsigned)f2b(hi) << 16);
}
// async 16B global -> LDS (lands at wave-uniform base + lane*16)
__device__ __forceinline__ void gload16(const ushort_t* g, ushort_t* l) {
    __builtin_amdgcn_global_load_lds(
        (const __attribute__((address_space(1))) unsigned int*)g,
        (__attribute__((address_space(3))) unsigned int*)l, 16, 0, 0);
}

#define WAITV(N) { asm volatile("s_waitcnt vmcnt(" #N ")" ::: "memory"); \
                   __builtin_amdgcn_sched_barrier(0); }
#define FENCE_LGKM { asm volatile("s_waitcnt lgkmcnt(0)" ::: "memory"); \
                     __builtin_amdgcn_sched_barrier(0); }

// ---------------------------------------------------------------------------
// Bias helper vectors: wqbk = Wq@bk, wkbq = Wk@bq, cc = bq.bk.
// grid (32,3), block 256.  (All zero for this problem's inputs, but exact.)
// ---------------------------------------------------------------------------
__global__ __launch_bounds__(256) void mv_bias_kernel(
    const float* __restrict__ Wq, const float* __restrict__ Wk,
    const float* __restrict__ bq, const float* __restrict__ bk,
    float* __restrict__ wqbk, float* __restrict__ wkbq, float* __restrict__ cc)
{
    __shared__ float ls[4];
    const int y = blockIdx.y;
    const int t = threadIdx.x;
    if (y == 2) {
        if (blockIdx.x != 0) return;
        float s = bq[t] * bk[t] + bq[t + 256] * bk[t + 256];
#pragma unroll
        for (int off = 32; off > 0; off >>= 1) s += __shfl_down(s, off, 64);
        int lane = t & 63, w = t >> 6;
        if (lane == 0) ls[w] = s;
        __syncthreads();
        if (t == 0) cc[0] = ls[0] + ls[1] + ls[2] + ls[3];
        return;
    }
    const float* W = y ? Wk : Wq;
    const float* v = y ? bq : bk;
    float* o = y ? wkbq : wqbk;
    const int row = blockIdx.x * 16 + (t >> 4);
    const int l = t & 15;
    const float* wr = W + (size_t)row * 512 + l * 32;
    const float* vr = v + l * 32;
    float s = 0.f;
#pragma unroll
    for (int c = 0; c < 32; ++c) s += wr[c] * vr[c];
#pragma unroll
    for (int off = 8; off > 0; off >>= 1) s += __shfl_down(s, off, 16);
    if (l == 0) o[row] = s;
}

// ---------------------------------------------------------------------------
// LayerNorm: stats + apply + bf16 store + dot with bias helper (t1/t2).
// grid (16384, 2), block 256.  Row = 512 floats, float2 per thread.
// ---------------------------------------------------------------------------
__global__ __launch_bounds__(256) void ln_apply_kernel(
    const float* __restrict__ X1, const float* __restrict__ X2,
    const float* __restrict__ g1, const float* __restrict__ b1,
    const float* __restrict__ g2, const float* __restrict__ b2,
    const float* __restrict__ wb1, const float* __restrict__ wb2,
    ushort_t* __restrict__ O1, ushort_t* __restrict__ O2,
    float* __restrict__ T1, float* __restrict__ T2)
{
    const bool sec = blockIdx.y != 0;
    const float* X = sec ? X2 : X1;
    const float* g = sec ? g2 : g1;
    const float* b = sec ? b2 : b1;
    const float* wb = sec ? wb2 : wb1;
    ushort_t* O = sec ? O2 : O1;
    float* T = sec ? T2 : T1;
    const size_t base = (size_t)blockIdx.x * 512;
    const int t = threadIdx.x;
    float2 x = ((const float2*)(X + base))[t];
    float s = x.x + x.y;
    float q = fmaf(x.x, x.x, x.y * x.y);
#pragma unroll
    for (int off = 32; off > 0; off >>= 1) {
        s += __shfl_down(s, off, 64);
        q += __shfl_down(q, off, 64);
    }
    __shared__ float ls[4], lq[4], mv[2], ld[4];
    int lane = t & 63, w = t >> 6;
    if (lane == 0) { ls[w] = s; lq[w] = q; }
    __syncthreads();
    if (t == 0) {
        float st = ls[0] + ls[1] + ls[2] + ls[3];
        float qt = lq[0] + lq[1] + lq[2] + lq[3];
        float mu = st * (1.0f / 512.0f);
        float var = qt * (1.0f / 512.0f) - mu * mu;
        mv[0] = mu;
        mv[1] = rsqrtf(var + LN_EPSF);
    }
    __syncthreads();
    const float mu = mv[0], rstd = mv[1];
    float2 gg = ((const float2*)g)[t];
    float2 bb = ((const float2*)b)[t];
    float2 ww = ((const float2*)wb)[t];
    float o0 = (x.x - mu) * rstd * gg.x + bb.x;
    float o1 = (x.y - mu) * rstd * gg.y + bb.y;
    ((unsigned*)O)[blockIdx.x * 256 + t] = pk2(o0, o1);
    float d = o0 * ww.x + o1 * ww.y;
#pragma unroll
    for (int off = 32; off > 0; off >>= 1) d += __shfl_down(d, off, 64);
    if (lane == 0) ld[w] = d;
    __syncthreads();
    if (t == 0) T[blockIdx.x] = ld[0] + ld[1] + ld[2] + ld[3];
}

// ---------------------------------------------------------------------------
// Weight prep: z=0,1 cast Wq,Wk -> bf16 (same layout); z=2 transpose Wv.
// grid (16,16,3), block 256.
// ---------------------------------------------------------------------------
__global__ __launch_bounds__(256) void wprep_kernel(
    const float* __restrict__ Wq, const float* __restrict__ Wk,
    const float* __restrict__ Wv,
    ushort_t* __restrict__ Wqb, ushort_t* __restrict__ Wkb,
    ushort_t* __restrict__ WvT)
{
    const int z = blockIdx.z;
    if (z < 2) {
        const float* W = z ? Wk : Wq;
        ushort_t* T = z ? Wkb : Wqb;
        size_t idx = ((size_t)(blockIdx.y * 16 + blockIdx.x)) * 1024 + threadIdx.x * 4;
        float4 f = *(const float4*)(W + idx);
        uint2 u;
        u.x = pk2(f.x, f.y);
        u.y = pk2(f.z, f.w);
        *(uint2*)(T + idx) = u;
        return;
    }
    __shared__ float tile[32][33];
    int tx = threadIdx.x & 31, ty = threadIdx.x >> 5;
    int r0 = blockIdx.y * 32, c0 = blockIdx.x * 32;
#pragma unroll
    for (int p = 0; p < 4; ++p)
        tile[ty + p * 8][tx] = Wv[(size_t)(r0 + ty + p * 8) * 512 + c0 + tx];
    __syncthreads();
#pragma unroll
    for (int p = 0; p < 4; ++p)
        WvT[(size_t)(c0 + ty + p * 8) * 512 + r0 + tx] = f2b(tile[tx][ty + p * 8]);
}

// ---------------------------------------------------------------------------
// colrecip[t] = 1/colsum[t] (+bf16 copy).  16384 elems, grid 64, block 256.
// ---------------------------------------------------------------------------
__global__ __launch_bounds__(256) void colrecip_kernel(
    const float* __restrict__ cs, float* __restrict__ cr,
    ushort_t* __restrict__ crs)
{
    int t = blockIdx.x * 256 + threadIdx.x;
    float r = 1.0f / cs[t];
    cr[t] = r;
    crs[t] = f2b(r);
}

// ---------------------------------------------------------------------------
// 256x256-tile edots GEMM, 512 threads / 8 waves, counted-vmcnt 2-deep
// pipeline (verified r6/r7: 57us; the r8 4-phase split regressed -- reverted).
// ---------------------------------------------------------------------------
__global__ __launch_bounds__(512) void gemm256_exp_kernel(
    const ushort_t* __restrict__ A, const ushort_t* __restrict__ B,
    ushort_t* __restrict__ Cout,
    const float* __restrict__ t1, const float* __restrict__ t2,
    const float* __restrict__ cc, float* __restrict__ colsum,
    int K, int N, size_t strideA, size_t strideB, size_t strideC,
    float scale)
{
    __shared__ __align__(16) ushort_t As0[256 * 64];   // 32 KB each
    __shared__ __align__(16) ushort_t As1[256 * 64];
    __shared__ __align__(16) ushort_t Bs0[256 * 64];
    __shared__ __align__(16) ushort_t Bs1[256 * 64];
    const int tid = threadIdx.x;

    // XCD-chunked bijective swizzle: grid (8,8,8) -> each XCD owns one batch.
    const int nbx = gridDim.x, nby = gridDim.y;
    const int nwg = nbx * nby * gridDim.z;
    int lin = blockIdx.x + nbx * (blockIdx.y + nby * blockIdx.z);
    int swz = (lin & 7) * (nwg >> 3) + (lin >> 3);
    const int sx = __builtin_ctz(nbx), sy = __builtin_ctz(nby);
    const int bx = swz & (nbx - 1);
    const int by = (swz >> sx) & (nby - 1);
    const int bz = swz >> (sx + sy);

    const ushort_t* Ab = A + strideA * bz;
    const ushort_t* Bb = B + strideB * bz;
    const int m0 = by * 256;
    const int n0 = bx * 256;
    const int wave = tid >> 6;
    const int lane = tid & 63;
    const int fm = lane & 15;
    const int fq = lane >> 4;
    const int fq4 = fq * 4;
    const int wm = (wave >> 2) * 128;      // 2 row-halves
    const int wn = (wave & 3) * 64;        // 4 col-quarters

    const int lrow = lane >> 3;            // 0..7
    const int lchunk = lane & 7;           // 0..7
    const int scs = lchunk ^ lrow;         // swizzled source chunk

    const ushort_t* aSrc[4]; const ushort_t* bSrc[4];
#pragma unroll
    for (int p = 0; p < 4; ++p) {
        int row = wave * 32 + p * 8 + lrow;     // 0..255
        aSrc[p] = Ab + (size_t)(m0 + row) * K + scs * 8;
        bSrc[p] = Bb + (size_t)(n0 + row) * K + scs * 8;
    }
    const int dOff = wave * 2048 + lane * 8;    // (wave*32+p*8)*64 + lane*8

    const int cBase = fq ^ (fm & 7);

    f32x4 acc[8][4];
#pragma unroll
    for (int i = 0; i < 8; ++i)
#pragma unroll
        for (int j = 0; j < 4; ++j) acc[i][j] = (f32x4){0.f, 0.f, 0.f, 0.f};

    auto stage = [&](ushort_t* Ad, ushort_t* Bd, int k0) {
#pragma unroll
        for (int p = 0; p < 4; ++p) {
            gload16(aSrc[p] + k0, Ad + dOff + p * 512);
            gload16(bSrc[p] + k0, Bd + dOff + p * 512);
        }
    };
    auto compute = [&](const ushort_t* Asb, const ushort_t* Bsb) {
#pragma unroll
        for (int s = 0; s < 2; ++s) {
            const int off = ((cBase ^ (s << 2)) << 3);
            bhalf8 af[8], bfr[4];
#pragma unroll
            for (int u = 0; u < 8; ++u)
                af[u] = *(const bhalf8*)(Asb + (wm + u * 16 + fm) * 64 + off);
#pragma unroll
            for (int u = 0; u < 4; ++u)
                bfr[u] = *(const bhalf8*)(Bsb + (wn + u * 16 + fm) * 64 + off);
#pragma unroll
            for (int i = 0; i < 8; ++i)
#pragma unroll
                for (int j = 0; j < 4; ++j)
                    acc[i][j] = __builtin_amdgcn_mfma_f32_16x16x32_bf16(
                        bfr[j], af[i], acc[i][j], 0, 0, 0);
        }
    };

    const int nk = K >> 6;                  // 8 (K=512); even, >=4
    stage(As0, Bs0, 0);
    stage(As1, Bs1, 64);
    for (int t = 0; t < nk - 2; t += 2) {
        WAITV(8);
        __builtin_amdgcn_s_barrier();       // tile t ready for all waves
        compute(As0, Bs0);
        FENCE_LGKM;
        __builtin_amdgcn_s_barrier();       // all waves done reading buf0
        stage(As0, Bs0, (t + 2) << 6);
        WAITV(8);
        __builtin_amdgcn_s_barrier();       // tile t+1 ready
        compute(As1, Bs1);
        FENCE_LGKM;
        __builtin_amdgcn_s_barrier();       // all waves done reading buf1
        stage(As1, Bs1, (t + 3) << 6);
    }
    WAITV(8);
    __builtin_amdgcn_s_barrier();
    compute(As0, Bs0);                      // tile nk-2
    WAITV(0);
    __builtin_amdgcn_s_barrier();
    compute(As1, Bs1);                      // tile nk-1

    // Epilogue: exp + bf16 store + colsum (identical math to verified MODE1).
    ushort_t* C = Cout + strideC * bz;
    const float cv = cc[0];
    f32x4 t2c[4];
#pragma unroll
    for (int nj = 0; nj < 4; ++nj) {
        float4 tv = *(const float4*)(t2 + (size_t)bz * 2048 +
                                     n0 + wn + nj * 16 + fq4);
        t2c[nj][0] = tv.x + cv;
        t2c[nj][1] = tv.y + cv;
        t2c[nj][2] = tv.z + cv;
        t2c[nj][3] = tv.w + cv;
    }
    float psum[4][4];
#pragma unroll
    for (int nj = 0; nj < 4; ++nj)
#pragma unroll
        for (int r = 0; r < 4; ++r) psum[nj][r] = 0.f;
#pragma unroll
    for (int mi = 0; mi < 8; ++mi) {
        const int row = m0 + wm + mi * 16 + fm;
        const float t1v = t1[(size_t)bz * 2048 + row];
        ushort_t* Cr = C + (size_t)row * N + n0 + wn + fq4;
#pragma unroll
        for (int nj = 0; nj < 4; ++nj) {
            ushort_t h0 = f2b(__expf((acc[mi][nj][0] + t1v + t2c[nj][0]) * scale));
            ushort_t h1 = f2b(__expf((acc[mi][nj][1] + t1v + t2c[nj][1]) * scale));
            ushort_t h2 = f2b(__expf((acc[mi][nj][2] + t1v + t2c[nj][2]) * scale));
            ushort_t h3 = f2b(__expf((acc[mi][nj][3] + t1v + t2c[nj][3]) * scale));
            uint2 u;
            u.x = (unsigned)h0 | ((unsigned)h1 << 16);
            u.y = (unsigned)h2 | ((unsigned)h3 << 16);
            *(uint2*)(Cr + nj * 16) = u;
            psum[nj][0] += b2f(h0);
            psum[nj][1] += b2f(h1);
            psum[nj][2] += b2f(h2);
            psum[nj][3] += b2f(h3);
        }
    }
    // reduce over rows within wave (fm = lane bits 0..3)
#pragma unroll
    for (int nj = 0; nj < 4; ++nj)
#pragma unroll
        for (int r = 0; r < 4; ++r) {
            float v = psum[nj][r];
            v += __shfl_xor(v, 1, 64);
            v += __shfl_xor(v, 2, 64);
            v += __shfl_xor(v, 4, 64);
            v += __shfl_xor(v, 8, 64);
            psum[nj][r] = v;
        }
    float* colpart = (float*)&As0[0];
    __syncthreads();
    if (tid < 256) colpart[tid] = 0.f;
    __syncthreads();
    if (fm == 0) {
#pragma unroll
        for (int nj = 0; nj < 4; ++nj)
#pragma unroll
            for (int r = 0; r < 4; ++r)
                atomicAdd(&colpart[wn + nj * 16 + fq4 + r], psum[nj][r]);
    }
    __syncthreads();
    if (tid < 256)
        atomicAdd(&colsum[(size_t)bz * 2048 + n0 + tid], colpart[tid]);
}

// ---------------------------------------------------------------------------
// 256x128-tile OUT GEMM, 512 threads / 8 waves, counted-vmcnt 3-DEEP
// pipeline.  out[m,n] = (sum_k E[m,k] vTs[n,k]) / (rowsum+eps), rowsum via
// MFMA side-column with bf16 colrecip staged in LDS.
// 3 buffers (A 3x32K + B 3x16K + crs 4K = 148 KB, still 1 block/CU): tiles
// t,t+1,t+2 in flight (18 loads, 6/tile); per step WAITV(12) -> oldest tile
// done; stage t+3 after the read-done barrier.  Loads get ~2 full compute
// phases to land (vs 1 in the 2-deep r7 version).  Requires nk%3==2, nk>=8
// (nk=32 here).  Epilogue identical to verified r7.
// ---------------------------------------------------------------------------
__global__ __launch_bounds__(512) void gemm_out256_kernel(
    const ushort_t* __restrict__ A, const ushort_t* __restrict__ B,
    float* __restrict__ Cout, const ushort_t* __restrict__ crs,
    int K, int N, size_t strideA, size_t strideB, size_t strideC)
{
    __shared__ __align__(16) ushort_t As0[256 * 64];   // 32 KB
    __shared__ __align__(16) ushort_t As1[256 * 64];   // 32 KB
    __shared__ __align__(16) ushort_t As2[256 * 64];   // 32 KB
    __shared__ __align__(16) ushort_t Bs0[128 * 64];   // 16 KB
    __shared__ __align__(16) ushort_t Bs1[128 * 64];   // 16 KB
    __shared__ __align__(16) ushort_t Bs2[128 * 64];   // 16 KB
    __shared__ __align__(16) ushort_t crs_lds[2048];   // 4 KB
    const int tid = threadIdx.x;

    // XCD-chunked bijective swizzle: grid (4,8,8) -> each XCD owns one batch.
    const int nbx = gridDim.x, nby = gridDim.y;
    const int nwg = nbx * nby * gridDim.z;
    int lin = blockIdx.x + nbx * (blockIdx.y + nby * blockIdx.z);
    int swz = (lin & 7) * (nwg >> 3) + (lin >> 3);
    const int sx = __builtin_ctz(nbx), sy = __builtin_ctz(nby);
    const int bx = swz & (nbx - 1);
    const int by = (swz >> sx) & (nby - 1);
    const int bz = swz >> (sx + sy);

    const ushort_t* Ab = A + strideA * bz;
    const ushort_t* Bb = B + strideB * bz;
    const int m0 = by * 256;
    const int n0 = bx * 128;
    const int wave = tid >> 6;
    const int lane = tid & 63;
    const int fm = lane & 15;
    const int fq = lane >> 4;
    const int fq4 = fq * 4;
    const int wm = (wave >> 1) * 64;       // 4 row-groups of 64
    const int wn = (wave & 1) * 64;        // 2 col-groups of 64

    const int lrow = lane >> 3;            // 0..7
    const int lchunk = lane & 7;           // 0..7
    const int scs = lchunk ^ lrow;         // swizzled source chunk

    const ushort_t* aSrc[4]; const ushort_t* bSrc[2];
#pragma unroll
    for (int p = 0; p < 4; ++p) {
        int row = wave * 32 + p * 8 + lrow;     // 0..255
        aSrc[p] = Ab + (size_t)(m0 + row) * K + scs * 8;
    }
#pragma unroll
    for (int p = 0; p < 2; ++p) {
        int row = wave * 16 + p * 8 + lrow;     // 0..127
        bSrc[p] = Bb + (size_t)(n0 + row) * K + scs * 8;
    }
    const int aOff = wave * 2048 + lane * 8;    // (wave*32+p*8)*64 + lane*8
    const int bOff = wave * 1024 + lane * 8;    // (wave*16+p*8)*64 + lane*8

    // bf16 colrecip -> LDS (one batch's 2048 entries), then full drain+barrier
    if (tid < 256) {
        uint4 c4 = *(const uint4*)(crs + (size_t)bz * 2048 + tid * 8);
        *(uint4*)&crs_lds[tid * 8] = c4;
    }
    __syncthreads();

    const int cBase = fq ^ (fm & 7);

    f32x4 acc[4][4];
    f32x4 sacc[4];
#pragma unroll
    for (int i = 0; i < 4; ++i) {
        sacc[i] = (f32x4){0.f, 0.f, 0.f, 0.f};
#pragma unroll
        for (int j = 0; j < 4; ++j) acc[i][j] = (f32x4){0.f, 0.f, 0.f, 0.f};
    }

    auto stage = [&](ushort_t* Ad, ushort_t* Bd, int k0) {
#pragma unroll
        for (int p = 0; p < 4; ++p)
            gload16(aSrc[p] + k0, Ad + aOff + p * 512);
#pragma unroll
        for (int p = 0; p < 2; ++p)
            gload16(bSrc[p] + k0, Bd + bOff + p * 512);
    };
    auto compute = [&](const ushort_t* Asb, const ushort_t* Bsb, int k0) {
#pragma unroll
        for (int s = 0; s < 2; ++s) {
            const int off = ((cBase ^ (s << 2)) << 3);
            bhalf8 af[4], bfr[4];
#pragma unroll
            for (int u = 0; u < 4; ++u) {
                af[u]  = *(const bhalf8*)(Asb + (wm + u * 16 + fm) * 64 + off);
                bfr[u] = *(const bhalf8*)(Bsb + (wn + u * 16 + fm) * 64 + off);
            }
#pragma unroll
            for (int i = 0; i < 4; ++i)
#pragma unroll
                for (int j = 0; j < 4; ++j)
                    acc[i][j] = __builtin_amdgcn_mfma_f32_16x16x32_bf16(
                        bfr[j], af[i], acc[i][j], 0, 0, 0);
            bhalf8 bc = *(const bhalf8*)&crs_lds[k0 + (s << 5) + (fq << 3)];
#pragma unroll
            for (int i = 0; i < 4; ++i)
                sacc[i] = __builtin_amdgcn_mfma_f32_16x16x32_bf16(
                    bc, af[i], sacc[i], 0, 0, 0);
        }
    };

#define OUT_STEP(AS, BS, TCUR, TSTAGE)                                       \
    WAITV(12);                                                               \
    __builtin_amdgcn_s_barrier();       /* tile TCUR ready */                \
    compute(AS, BS, (TCUR) << 6);                                            \
    FENCE_LGKM;                                                              \
    __builtin_amdgcn_s_barrier();       /* all waves done with this buf */   \
    stage(AS, BS, (TSTAGE) << 6);

    const int nk = K >> 6;                  // 32 (K=2048); nk%3==2, nk>=8
    stage(As0, Bs0, 0);
    stage(As1, Bs1, 64);
    stage(As2, Bs2, 128);
    int t = 0;
    for (; t < nk - 5; t += 3) {
        OUT_STEP(As0, Bs0, t,     t + 3);
        OUT_STEP(As1, Bs1, t + 1, t + 4);
        OUT_STEP(As2, Bs2, t + 2, t + 5);
    }
    // t = nk-5: tiles t..nk-1 remain; staged through t+2.
    OUT_STEP(As0, Bs0, t,     t + 3);       // stages tile nk-2 -> buf0
    OUT_STEP(As1, Bs1, t + 1, t + 4);       // stages tile nk-1 -> buf1
    WAITV(12);
    __builtin_amdgcn_s_barrier();
    compute(As2, Bs2, (t + 2) << 6);        // tile nk-3
    FENCE_LGKM;
    __builtin_amdgcn_s_barrier();
    WAITV(6);
    __builtin_amdgcn_s_barrier();
    compute(As0, Bs0, (t + 3) << 6);        // tile nk-2
    FENCE_LGKM;
    __builtin_amdgcn_s_barrier();
    WAITV(0);
    __builtin_amdgcn_s_barrier();
    compute(As1, Bs1, (t + 4) << 6);        // tile nk-1
#undef OUT_STEP

    // Epilogue (identical math to verified r7): divide by rowsum, f32x4.
    float* C = Cout + strideC * bz;
#pragma unroll
    for (int ti = 0; ti < 4; ++ti) {
        const int row = m0 + wm + ti * 16 + fm;
        const float rs = 1.0f / (sacc[ti][0] + 2.049e-5f);
        float* Cr = C + (size_t)row * N + n0 + wn + fq4;
#pragma unroll
        for (int tj = 0; tj < 4; ++tj) {
            f32x4 v;
#pragma unroll
            for (int r = 0; r < 4; ++r) v[r] = acc[ti][tj][r] * rs;
            *(f32x4*)(Cr + tj * 16) = v;
        }
    }
}

// ---------------------------------------------------------------------------
// NT bf16 MFMA GEMM: C[m,n] = sum_k A[m,k]*B[n,k], k-major bf16, m97-style
// staging (BK=64, global_load_lds 16B, XOR chunk swizzle, conflict-free).
// 128x128 tile, 4 waves, 4x4 MFMA 16x16x32 each, swapped operands.
// XCD-chunked block swizzle (verified r5: FETCH halved).
// MODE 0: plain bf16 store (pk2, 8B)               (M = Wq Wk^T;  KM = cln M^T)
// MODE 3: (acc + bias[row]) * crcol[col], pk2 bf16 store             (vTs)
// ---------------------------------------------------------------------------
template <int MODE>
__global__ __launch_bounds__(256) void mfma_gemm_kernel(
    const ushort_t* __restrict__ A, const ushort_t* __restrict__ B,
    void* __restrict__ Cout,
    const float* __restrict__ bias,     // MODE3: row bias (bv)
    const float* __restrict__ crcol,    // MODE3: f32 colrecip
    int K, int N, size_t strideA, size_t strideB, size_t strideC)
{
    __shared__ __align__(16) ushort_t As[128 * 64];   // 16 KB
    __shared__ __align__(16) ushort_t Bs[128 * 64];   // 16 KB
    const int tid = threadIdx.x;

    // ---- XCD-chunked bijective block swizzle (all dims are powers of 2) ----
    const int nbx = gridDim.x, nby = gridDim.y, nbz = gridDim.z;
    const int nwg = nbx * nby * nbz;
    int bx, by, bz;
    if ((nwg & 7) == 0) {
        int lin = blockIdx.x + nbx * (blockIdx.y + nby * blockIdx.z);
        int swz = (lin & 7) * (nwg >> 3) + (lin >> 3);
        const int sx = __builtin_ctz(nbx), sy = __builtin_ctz(nby);
        bx = swz & (nbx - 1);
        by = (swz >> sx) & (nby - 1);
        bz = swz >> (sx + sy);
    } else {
        bx = blockIdx.x; by = blockIdx.y; bz = blockIdx.z;
    }

    const ushort_t* Ab = A + strideA * bz;
    const ushort_t* Bb = B + strideB * bz;
    const int m0 = by * 128;
    const int n0 = bx * 128;
    const int wave = tid >> 6;
    const int lane = tid & 63;
    const int fm = lane & 15;
    const int fq = lane >> 4;
    const int fq4 = fq * 4;
    const int fm7 = fm & 7;
    const int wm = (wave >> 1) * 64;
    const int wn = (wave & 1) * 64;

    const int lrow = lane >> 3;            // 0..7
    const int lchunk = lane & 7;           // 0..7
    const int scs = lchunk ^ lrow;         // swizzled source chunk

    const ushort_t* aSrc[4]; const ushort_t* bSrc[4];
    ushort_t* aDst[4]; ushort_t* bDst[4];
#pragma unroll
    for (int p = 0; p < 4; ++p) {
        int row = wave * 32 + p * 8 + lrow;
        aSrc[p] = Ab + (size_t)(m0 + row) * K + scs * 8;
        bSrc[p] = Bb + (size_t)(n0 + row) * K + scs * 8;
        aDst[p] = As + (wave * 32 + p * 8) * 64 + lane * 8;
        bDst[p] = Bs + (wave * 32 + p * 8) * 64 + lane * 8;
    }

    const int cBase = fq ^ fm7;
    const ushort_t* aFrag[4]; const ushort_t* bFrag[4];
#pragma unroll
    for (int t = 0; t < 4; ++t) {
        aFrag[t] = As + (wm + t * 16 + fm) * 64;
        bFrag[t] = Bs + (wn + t * 16 + fm) * 64;
    }

    f32x4 acc[4][4];
#pragma unroll
    for (int i = 0; i < 4; ++i)
#pragma unroll
        for (int j = 0; j < 4; ++j) acc[i][j] = (f32x4){0.f, 0.f, 0.f, 0.f};

    for (int k0 = 0; k0 < K; k0 += 64) {
        __syncthreads();
#pragma unroll
        for (int p = 0; p < 4; ++p) {
            gload16(aSrc[p] + k0, aDst[p]);
            gload16(bSrc[p] + k0, bDst[p]);
        }
        __syncthreads();
#pragma unroll
        for (int s = 0; s < 2; ++s) {
            const int off = ((cBase ^ (s << 2)) << 3);
            bhalf8 af[4], bfr[4];
#pragma unroll
            for (int u = 0; u < 4; ++u) {
                af[u]  = *(const bhalf8*)(aFrag[u] + off);
                bfr[u] = *(const bhalf8*)(bFrag[u] + off);
            }
#pragma unroll
            for (int i = 0; i < 4; ++i)
#pragma unroll
                for (int j = 0; j < 4; ++j)
                    acc[i][j] = __builtin_amdgcn_mfma_f32_16x16x32_bf16(
                        bfr[j], af[i], acc[i][j], 0, 0, 0);
        }
    }

    // acc[ti][tj][r] = C[i][j], i = m0+wm+ti*16+fm, j = n0+wn+tj*16+fq4+r
    if (MODE == 3) {
        ushort_t* C = (ushort_t*)Cout + strideC * bz;
        f32x4 crv[4];
#pragma unroll
        for (int tj = 0; tj < 4; ++tj) {
            float4 cq = *(const float4*)(crcol + (size_t)bz * 2048 +
                                         n0 + wn + tj * 16 + fq4);
            crv[tj][0] = cq.x; crv[tj][1] = cq.y;
            crv[tj][2] = cq.z; crv[tj][3] = cq.w;
        }
#pragma unroll
        for (int ti = 0; ti < 4; ++ti) {
            const int row = m0 + wm + ti * 16 + fm;
            const float bvv = bias[row];
            ushort_t* Cr = C + (size_t)row * N + n0 + wn + fq4;
#pragma unroll
            for (int tj = 0; tj < 4; ++tj) {
                uint2 u;
                u.x = pk2((acc[ti][tj][0] + bvv) * crv[tj][0],
                          (acc[ti][tj][1] + bvv) * crv[tj][1]);
                u.y = pk2((acc[ti][tj][2] + bvv) * crv[tj][2],
                          (acc[ti][tj][3] + bvv) * crv[tj][3]);
                *(uint2*)(Cr + tj * 16) = u;
            }
        }
    } else {
        ushort_t* C = (ushort_t*)Cout + strideC * bz;
#pragma unroll
        for (int ti = 0; ti < 4; ++ti) {
            const int row = m0 + wm + ti * 16 + fm;
            ushort_t* Cr = C + (size_t)row * N + n0 + wn + fq4;
#pragma unroll
            for (int tj = 0; tj < 4; ++tj) {
                uint2 u;
                u.x = pk2(acc[ti][tj][0], acc[ti][tj][1]);
                u.y = pk2(acc[ti][tj][2], acc[ti][tj][3]);
                *(uint2*)(Cr + tj * 16) = u;
            }
        }
    }
}

// ---------------------------------------------------------------------------
extern "C" void kernel_launch(void* const* d_in, const int* in_sizes, int n_in,
                              void* d_out, int out_size, void* d_ws, size_t ws_size,
                              hipStream_t stream)
{
    const float* inputs  = (const float*)d_in[0];
    const float* context = (const float*)d_in[1];
    const float* g_in    = (const float*)d_in[2];
    const float* b_in    = (const float*)d_in[3];
    const float* g_ctx   = (const float*)d_in[4];
    const float* b_ctx   = (const float*)d_in[5];
    const float* Wq      = (const float*)d_in[6];
    const float* bq      = (const float*)d_in[7];
    const float* Wk      = (const float*)d_in[8];
    const float* bk      = (const float*)d_in[9];
    const float* Wv      = (const float*)d_in[10];
    const float* bv      = (const float*)d_in[11];
    float* out = (float*)d_out;                      // [8,2048,512] fp32

    const size_t QKV  = 8ull * 2048 * 512;           // 8,388,608
    const size_t WSZ  = 512ull * 512;                // 262,144
    const size_t DOTS = 8ull * 2048 * 2048;          // 33,554,432

    ushort_t* xln   = (ushort_t*)d_ws;
    ushort_t* cln   = xln + QKV;
    ushort_t* Wqb   = cln + QKV;
    ushort_t* Wkb   = Wqb + WSZ;
    ushort_t* WvT   = Wkb + WSZ;
    ushort_t* Mb    = WvT + WSZ;                     // Wq Wk^T, bf16 [512][512]
    ushort_t* KM    = Mb + WSZ;                      // cln M^T [16384][512]
    ushort_t* vTs   = KM + QKV;                      // (cln Wv + bv)^T * cr
    ushort_t* edots = vTs + QKV;
    ushort_t* crs   = edots + DOTS;                  // bf16 colrecip [16384]
    float* fbase    = (float*)(crs + 16384);
    float* colsum   = fbase;                         // 16384
    float* colrecip = colsum + 16384;                // 16384
    float* t1       = colrecip + 16384;              // 16384
    float* t2       = t1 + 16384;                    // 16384
    float* wqbk     = t2 + 16384;                    // 512
    float* wkbq     = wqbk + 512;                    // 512
    float* cc       = wkbq + 512;                    // 1
    size_t need_bytes = (4 * QKV + 4 * WSZ + DOTS + 16384) * 2
                      + (4 * 16384 + 1024 + 1) * 4;
    if (ws_size < need_bytes) return;  // fail loudly via validation mismatch

    hipMemsetAsync(colsum, 0, 16384 * sizeof(float), stream);

    mv_bias_kernel<<<dim3(32, 3), 256, 0, stream>>>(Wq, Wk, bq, bk, wqbk, wkbq, cc);

    ln_apply_kernel<<<dim3(16384, 2), 256, 0, stream>>>(
        inputs, context, g_in, b_in, g_ctx, b_ctx, wqbk, wkbq, xln, cln, t1, t2);

    wprep_kernel<<<dim3(16, 16, 3), 256, 0, stream>>>(Wq, Wk, Wv, Wqb, Wkb, WvT);

    // M = Wq @ Wk^T   [512,512]
    mfma_gemm_kernel<0><<<dim3(4, 4, 1), 256, 0, stream>>>(
        Wqb, Wkb, Mb, nullptr, nullptr,
        512, 512, 0, 0, 0);

    // KM[j][a] = sum_b cln[j,b] M[a,b]   [16384,512]
    mfma_gemm_kernel<0><<<dim3(4, 128, 1), 256, 0, stream>>>(
        cln, Mb, KM, nullptr, nullptr,
        512, 512, 0, 0, 0);

    // edots = exp(scale*(xln KM^T + t1 + t2 + cc)), column sums -> colsum
    gemm256_exp_kernel<<<dim3(8, 8, 8), 512, 0, stream>>>(
        xln, KM, edots, t1, t2, cc, colsum,
        512, 2048, (size_t)2048 * 512, (size_t)2048 * 512, (size_t)2048 * 2048,
        SCALE_QK);

    colrecip_kernel<<<64, 256, 0, stream>>>(colsum, colrecip, crs);

    // vTs[b,d,j] = (sum_b' WvT[d,b'] cln[j,b'] + bv[d]) * colrecip[b,j]
    mfma_gemm_kernel<3><<<dim3(16, 4, 8), 256, 0, stream>>>(
        WvT, cln, vTs, bv, colrecip,
        512, 2048, 0, (size_t)2048 * 512, (size_t)512 * 2048);

    // out = diag(1/(E cr + eps)) * E @ vTs^T   (rowsum via MFMA side-column)
    // 256x128-tile counted-vmcnt 3-deep pipeline, 512 threads, grid (4,8,8)
    gemm_out256_kernel<<<dim3(4, 8, 8), 512, 0, stream>>>(
        edots, vTs, out, crs,
        2048, 512, (size_t)2048 * 2048, (size_t)512 * 2048, (size_t)2048 * 512);
}